// Round 10
// baseline (668.436 us; speedup 1.0000x reference)
//
#include <hip/hip_runtime.h>
#include <hip/hip_bf16.h>

#define EPS_BN 1e-5f

constexpr int B  = 2048, F0 = 64, K = 14;
constexpr int C1 = 64,  F1 = 32;
constexpr int C2 = 128, F2 = 16;
constexpr int C3 = 256, F3 = 8;

typedef __attribute__((ext_vector_type(8))) short bf16x8;
typedef __attribute__((ext_vector_type(4))) float f32x4;

__device__ __forceinline__ float bf2f(unsigned short u) {
    union { unsigned int i; float f; } x; x.i = ((unsigned int)u) << 16; return x.f;
}
__device__ __forceinline__ unsigned short f2bf(float f) {
    union { float f; unsigned int i; } x; x.f = f;
    unsigned int r = (x.i + 0x7fffu + ((x.i >> 16) & 1u)) >> 16;
    return (unsigned short)r;
}

// async global->LDS 16B copy. HW: LDS dest = wave-uniform base + lane*16.
// Callers must keep whole waves active with per-lane-consecutive dests.
__device__ __forceinline__ void gl_lds16(const void* g, void* l) {
    __builtin_amdgcn_global_load_lds(
        (const __attribute__((address_space(1))) unsigned int*)g,
        (__attribute__((address_space(3))) unsigned int*)l,
        16, 0, 0);
}

// ---- fold BN into conv1 weights; also zero the 16B pad-source block ----
__global__ void repack_w1(const float* __restrict__ w1, const float* __restrict__ g,
                          const float* __restrict__ bb, const float* __restrict__ m,
                          const float* __restrict__ v, float* __restrict__ w1f,
                          float* __restrict__ t1, float* __restrict__ zbuf) {
    int i = blockIdx.x * 256 + threadIdx.x;
    if (i < 4) zbuf[i] = 0.0f;
    if (i < C1) {
        float s = g[i] * rsqrtf(v[i] + EPS_BN);
        t1[i] = bb[i] - m[i] * s;
    }
    if (i < C1 * 2 * 9) {
        int c = i / 18;
        float s = g[c] * rsqrtf(v[c] + EPS_BN);
        w1f[i] = w1[i] * s;
    }
}

// ---- repack conv weights into MFMA B-fragment layout, bf16, BN-folded ----
// wp[((chunk*COUT + n)*32) + kk] = W[tap][ci][n]*s[n], chunk=tap*(CIN/32)+cc, ci=cc*32+kk
template<int CIN, int COUT>
__global__ void repack_mfma(const float* __restrict__ w, const float* __restrict__ g,
                            const float* __restrict__ bb, const float* __restrict__ m,
                            const float* __restrict__ v, unsigned short* __restrict__ wp,
                            float* __restrict__ t) {
    int idx = blockIdx.x * 256 + threadIdx.x;
    if (idx < COUT) {
        float s = g[idx] * rsqrtf(v[idx] + EPS_BN);
        t[idx] = bb[idx] - m[idx] * s;
    }
    if (idx < 9 * CIN * COUT) {
        constexpr int CCS = CIN / 32;
        int kk = idx & 31;
        int rest = idx >> 5;
        int n = rest & (COUT - 1);
        int chunk = rest / COUT;
        int tap = chunk / CCS;
        int cc  = chunk & (CCS - 1);
        int ci = cc * 32 + kk;
        float s = g[n] * rsqrtf(v[n] + EPS_BN);
        wp[idx] = f2bf(w[(n * CIN + ci) * 9 + tap] * s);
    }
}

// ---- conv1 (2->64, 3x3, stride (2,1), pad 1) + BN + ReLU, NHWC bf16 out ----
__global__ void conv1_kernel(const float* __restrict__ x, const float* __restrict__ sig,
                             const float* __restrict__ w1f, const float* __restrict__ t1,
                             unsigned short* __restrict__ h1) {
    __shared__ float xs[F0 * K], ssg[F0 * K], wsh[C1 * 19], bsh[C1];
    int b = blockIdx.x, t = threadIdx.x;
    for (int i = t; i < F0 * K; i += 256) {
        xs[i]  = x[(size_t)b * F0 * K + i];
        ssg[i] = sig[(size_t)b * F0 * K + i] * 10.0f;
    }
    for (int i = t; i < C1 * 18; i += 256) {
        int c = i / 18, r = i % 18;
        wsh[c * 19 + r] = w1f[i];
    }
    if (t < C1) bsh[t] = t1[t];
    __syncthreads();
    int c = t & 63, pg = t >> 6;
    for (int p = pg; p < F1 * K; p += 4) {
        int f = p / K, k = p % K;
        float acc = bsh[c];
        #pragma unroll
        for (int df = 0; df < 3; ++df) {
            int fi = 2 * f + df - 1;
            if (fi < 0 || fi >= F0) continue;
            #pragma unroll
            for (int dk = 0; dk < 3; ++dk) {
                int ki = k + dk - 1;
                if (ki < 0 || ki >= K) continue;
                acc = fmaf(xs[fi * K + ki],  wsh[c * 19 + df * 3 + dk], acc);
                acc = fmaf(ssg[fi * K + ki], wsh[c * 19 + 9 + df * 3 + dk], acc);
            }
        }
        h1[(((size_t)b * F1 + f) * K + k) * C1 + c] = f2bf(fmaxf(acc, 0.f));
    }
}

// ---- conv2 as MFMA GEMM: round-2 structure VERBATIM (proven 76 VGPR, no
// spill). G=4 per-(g,df) tiles, flat it-loop, 2-deep bv rotation.
template<int CIN, int COUT, int FIN, int MINW>
__launch_bounds__(256, MINW)
__global__ void conv_mfma(const unsigned short* __restrict__ hin,
                          const unsigned short* __restrict__ wp,
                          const float* __restrict__ tb,
                          const unsigned short* __restrict__ zero16,
                          unsigned short* __restrict__ hout) {
    constexpr int G = 4;
    constexpr int CHW = CIN / 8;             // 16B chunks per row
    constexpr int LOGC = (CHW == 16) ? 4 : 3;
    constexpr int NT = COUT / 64;
    constexpr int CCS = CIN / 32;
    constexpr int NIT = 9 * CCS;             // 18 (conv2) / 36 (conv3), even
    __shared__ alignas(16) unsigned short lin[G * 3 * 16 * CIN];

    const int b = blockIdx.y;
    const int f2base = blockIdx.x * G;
    const int t = threadIdx.x;

    // async stage: LDS chunk i holds global chunk (c8 ^ (p&7)) of row (fi,kin).
    // Pad rows stage zeros from zero16. All lanes active on every call.
    {
        constexpr int TOT = G * 3 * 16 * CHW;            // multiple of 256
        #pragma unroll
        for (int i = t; i < TOT; i += 256) {
            int c8 = i & (CHW - 1);
            int row = i >> LOGC;
            int p = row & 15;
            int tile = row >> 4;
            int df = tile % 3, g = tile / 3;
            int kin = p - 1;
            int fi = 2 * (f2base + g) + df - 1;          // fi < FIN always
            bool valid = (kin >= 0) & (kin < K) & (fi >= 0);
            const unsigned short* src = valid
                ? hin + (((size_t)(b * FIN + fi)) * K + kin) * CIN + ((c8 ^ (p & 7)) << 3)
                : zero16;
            gl_lds16(src, &lin[i * 8]);
        }
    }
    __syncthreads();   // drains vmcnt (gload_lds)

    const int lane = t & 63;
    const int wave = t >> 6;
    const int m = lane & 15;                 // A row / B col / D col
    const int quad = lane >> 4;
    const int nBase = wave * (COUT / 4);

    f32x4 acc[G][NT];
    #pragma unroll
    for (int nt = 0; nt < NT; ++nt) {
        float bias = tb[nBase + nt * 16 + m];
        #pragma unroll
        for (int g = 0; g < G; ++g)
            acc[g][nt] = f32x4{bias, bias, bias, bias};
    }

    // it -> (df, dk, cc)
    auto loadA = [&](int it, bf16x8* av) {
        int df = it / (3 * CCS), dk = (it / CCS) % 3, cc = it % CCS;
        int p = m + dk; p = (p > 15) ? 15 : p;           // clamped lanes hit zero row
        int cidx = (((cc * 4 + quad) ^ (p & 7)) << 3);
        #pragma unroll
        for (int g = 0; g < G; ++g)
            av[g] = *(const bf16x8*)&lin[((g * 3 + df) * 16 + p) * CIN + cidx];
    };
    auto loadB = [&](int it, bf16x8* bv) {
        int df = it / (3 * CCS), dk = (it / CCS) % 3, cc = it % CCS;
        int chunk = (df * 3 + dk) * CCS + cc;
        #pragma unroll
        for (int nt = 0; nt < NT; ++nt)
            bv[nt] = *(const bf16x8*)(wp + (((chunk * COUT + nBase + nt * 16 + m)) << 5) + quad * 8);
    };
    auto domfma = [&](bf16x8* av, bf16x8* bv) {
        #pragma unroll
        for (int g = 0; g < G; ++g)
            #pragma unroll
            for (int nt = 0; nt < NT; ++nt)
                acc[g][nt] = __builtin_amdgcn_mfma_f32_16x16x32_bf16(av[g], bv[nt], acc[g][nt], 0, 0, 0);
    };

    bf16x8 av[G], bA[NT], bB[NT];
    loadB(0, bA);
    #pragma unroll
    for (int it = 0; it < NIT; it += 2) {
        loadB(it + 1, bB);           // prefetch for second half
        loadA(it, av);
        domfma(av, bA);
        if (it + 2 < NIT) loadB(it + 2, bA);   // prefetch next pair's first half
        loadA(it + 1, av);
        domfma(av, bB);
    }

    // epilogue: D[row=quad*4+i][col=m], ReLU, bf16 NHWC store; rows 14,15 = pad
    #pragma unroll
    for (int g = 0; g < G; ++g) {
        size_t rowbase = ((size_t)(b * (FIN / 2) + f2base + g)) * K;
        #pragma unroll
        for (int nt = 0; nt < NT; ++nt) {
            int col = nBase + nt * 16 + m;
            #pragma unroll
            for (int i = 0; i < 4; ++i) {
                int row = quad * 4 + i;
                if (row < K)
                    hout[(rowbase + row) * COUT + col] = f2bf(fmaxf(acc[g][nt][i], 0.f));
            }
        }
    }
}

// ---- conv3 as MFMA GEMM, wide: 1024 threads, G=8, by-fi planes ----
// Body correctness-proven (rounds 8/9). Register fix: the allocator budgets
// for the MAX occupancy LDS permits (69.6KB -> 2 blk/CU -> 8 waves/EU -> 64
// regs -> spill storm; launch_bounds 2nd arg only sets the MIN). Pin the MAX
// with amdgpu_waves_per_eu(4,4) -> budget 512/4 = 128 regs (demand ~102).
// Belt-and-braces: opaquely-guarded LDS pad pushes block >81920B so the
// LDS-derived occupancy bound is also 4 waves/EU.
template<int CIN, int COUT, int FIN, int G>
__global__ __launch_bounds__(1024) __attribute__((amdgpu_waves_per_eu(4, 4)))
void conv_mfma_wide(const unsigned short* __restrict__ hin,
                    const unsigned short* __restrict__ wp,
                    const float* __restrict__ tb,
                    const unsigned short* __restrict__ zero16,
                    unsigned short* __restrict__ hout) {
    constexpr int CHW = CIN / 8;             // 16B chunks per input row
    constexpr int LOGC = (CHW == 16) ? 4 : 3;
    constexpr int NP = 2 * G + 1;            // fi planes: pf = fi+1 in [0, 2G]
    constexpr int CCS = CIN / 32;
    constexpr int NIT = 9 * CCS;             // weight chunk count (36)
    constexpr int AG = 4;                    // g's per wave
    constexpr int NT = 2;                    // 16-col tiles per wave (32 cols)
    constexpr int NCS = COUT / 32;           // colsets
    static_assert((G / AG) * NCS == 16, "need 16 waves");
    __shared__ alignas(16) unsigned short lin[NP * 16 * CIN];
    __shared__ char ldspad[12416];           // push LDS > 81920B -> 1 blk/CU

    const int b = blockIdx.x;
    const int t = threadIdx.x;
    if ((size_t)zero16 == 1) ldspad[t] = 1;  // opaque guard: never true, keeps pad alive

    // async input stage: plane pf (fi=pf-1), row p (kin=p-1), chunk c8
    // pre-swizzled (c8^(p&7)). Pad rows pull from the zeroed global block.
    constexpr int TOT = NP * 16 * CHW;
    for (int i = t; i < TOT; i += 1024) {
        int c8 = i & (CHW - 1);
        int row = i >> LOGC;
        int p = row & 15;
        int pf = row >> 4;
        int kin = p - 1;
        int fi = pf - 1;                     // fi in [-1, FIN-1]
        bool valid = (kin >= 0) & (kin < K) & (fi >= 0);
        const unsigned short* src = valid
            ? hin + (((size_t)(b * FIN + fi)) * K + kin) * CIN + ((c8 ^ (p & 7)) << 3)
            : zero16;
        gl_lds16(src, &lin[i * 8]);
    }
    __syncthreads();

    const int lane = t & 63;
    const int wave = t >> 6;                 // 0..15
    const int m = lane & 15;                 // A row / B col / D col
    const int quad = lane >> 4;
    const int colset = wave % NCS;
    const int gBase = (wave / NCS) * AG;
    const int nBase = colset * 32;

    f32x4 acc[AG][NT];
    #pragma unroll
    for (int nt = 0; nt < NT; ++nt) {
        float bias = tb[nBase + nt * 16 + m];
        #pragma unroll
        for (int g = 0; g < AG; ++g)
            acc[g][nt] = f32x4{bias, bias, bias, bias};
    }

    bf16x8 bv[NT];
    #pragma unroll
    for (int it = 0; it < NIT; ++it) {
        const int df = it / (3 * CCS), dk = (it / CCS) % 3, cc = it % CCS;
        int p = m + dk; p = (p > 15) ? 15 : p;           // clamp -> zero pad row
        const int cidx = (((cc * 4 + quad) ^ (p & 7)) << 3);
        #pragma unroll
        for (int nt = 0; nt < NT; ++nt)
            bv[nt] = *(const bf16x8*)(wp + (((it * COUT + nBase + nt * 16 + m)) << 5) + quad * 8);
        #pragma unroll
        for (int g = 0; g < AG; ++g) {
            bf16x8 av = *(const bf16x8*)&lin[((2 * (gBase + g) + df) * 16 + p) * CIN + cidx];
            #pragma unroll
            for (int nt = 0; nt < NT; ++nt)
                acc[g][nt] = __builtin_amdgcn_mfma_f32_16x16x32_bf16(av, bv[nt], acc[g][nt], 0, 0, 0);
        }
    }

    // epilogue: D[row=quad*4+i][col=m], ReLU, bf16 NHWC store; rows 14,15 = pad
    #pragma unroll
    for (int g = 0; g < AG; ++g) {
        size_t rowbase = ((size_t)(b * (FIN / 2) + gBase + g)) * K;
        #pragma unroll
        for (int nt = 0; nt < NT; ++nt) {
            int col = nBase + nt * 16 + m;
            #pragma unroll
            for (int i = 0; i < 4; ++i) {
                int row = quad * 4 + i;
                if (row < K)
                    hout[(rowbase + row) * COUT + col] = f2bf(fmaxf(acc[g][nt][i], 0.f));
            }
        }
    }
}

// ---- conv4 (256->2, kernel (8,1)) + transpose to [B,K,2], vectorized ----
__global__ void conv4_kernel(const unsigned short* __restrict__ h3,
                             const float* __restrict__ w4, float* __restrict__ out) {
    int b = blockIdx.x;
    int t = threadIdx.x;              // 256
    int c32 = t & 31;                 // channel chunk of 8
    int f = t >> 5;                   // frame 0..7
    int c0 = c32 * 8;
    float wa[8], wb[8];
    #pragma unroll
    for (int j = 0; j < 8; ++j) {
        wa[j] = w4[((0 * C3) + c0 + j) * 8 + f];
        wb[j] = w4[((1 * C3) + c0 + j) * 8 + f];
    }
    const unsigned short* base = h3 + ((size_t)(b * F3 + f) * K) * C3 + c0;
    float p0[K], p1[K];
    #pragma unroll
    for (int k = 0; k < K; ++k) {
        bf16x8 v = *(const bf16x8*)(base + k * C3);
        float s0 = 0.f, s1 = 0.f;
        #pragma unroll
        for (int j = 0; j < 8; ++j) {
            float xv = bf2f((unsigned short)v[j]);
            s0 = fmaf(xv, wa[j], s0);
            s1 = fmaf(xv, wb[j], s1);
        }
        p0[k] = s0; p1[k] = s1;
    }
    #pragma unroll
    for (int k = 0; k < K; ++k) {
        #pragma unroll
        for (int off = 16; off > 0; off >>= 1) {
            p0[k] += __shfl_down(p0[k], off, 32);
            p1[k] += __shfl_down(p1[k], off, 32);
        }
    }
    __shared__ float red[F3][2 * K];
    if (c32 == 0) {
        #pragma unroll
        for (int k = 0; k < K; ++k) {
            red[f][2 * k + 0] = p0[k];
            red[f][2 * k + 1] = p1[k];
        }
    }
    __syncthreads();
    if (t < 2 * K) {
        float s = 0.f;
        #pragma unroll
        for (int ff = 0; ff < F3; ++ff) s += red[ff][t];
        out[b * (2 * K) + t] = s;
    }
}

extern "C" void kernel_launch(void* const* d_in, const int* in_sizes, int n_in,
                              void* d_out, int out_size, void* d_ws, size_t ws_size,
                              hipStream_t stream) {
    const float* x   = (const float*)d_in[0];
    const float* sig = (const float*)d_in[1];
    const float* w1  = (const float*)d_in[2];
    const float* w2  = (const float*)d_in[3];
    const float* w3  = (const float*)d_in[4];
    const float* w4  = (const float*)d_in[5];
    const float* g1  = (const float*)d_in[6];
    const float* b1  = (const float*)d_in[7];
    const float* m1  = (const float*)d_in[8];
    const float* v1  = (const float*)d_in[9];
    const float* g2  = (const float*)d_in[10];
    const float* b2  = (const float*)d_in[11];
    const float* m2  = (const float*)d_in[12];
    const float* v2  = (const float*)d_in[13];
    const float* g3  = (const float*)d_in[14];
    const float* b3  = (const float*)d_in[15];
    const float* m3  = (const float*)d_in[16];
    const float* v3  = (const float*)d_in[17];

    char* ws = (char*)d_ws;
    size_t off = 0;
    auto alloc = [&](size_t bytes) {
        char* p = ws + off;
        off += (bytes + 255) & ~(size_t)255;
        return p;
    };
    unsigned short* h1  = (unsigned short*)alloc((size_t)B * F1 * K * C1 * 2);  // reused as h3
    unsigned short* h2  = (unsigned short*)alloc((size_t)B * F2 * K * C2 * 2);
    float* w1f = (float*)alloc((size_t)C1 * 2 * 9 * 4);
    float* t1  = (float*)alloc((size_t)C1 * 4);
    unsigned short* wp2 = (unsigned short*)alloc((size_t)9 * C1 * C2 * 2);
    float* t2  = (float*)alloc((size_t)C2 * 4);
    unsigned short* wp3 = (unsigned short*)alloc((size_t)9 * C2 * C3 * 2);
    float* t3  = (float*)alloc((size_t)C3 * 4);
    float* zbuf = (float*)alloc(16);
    unsigned short* h3 = h1;

    repack_w1<<<(C1 * 2 * 9 + 255) / 256, 256, 0, stream>>>(w1, g1, b1, m1, v1, w1f, t1, zbuf);
    repack_mfma<C1, C2><<<(9 * C1 * C2 + 255) / 256, 256, 0, stream>>>(w2, g2, b2, m2, v2, wp2, t2);
    repack_mfma<C2, C3><<<(9 * C2 * C3 + 255) / 256, 256, 0, stream>>>(w3, g3, b3, m3, v3, wp3, t3);

    conv1_kernel<<<B, 256, 0, stream>>>(x, sig, w1f, t1, h1);
    // conv2: round-2 structure, G=4 -> grid (4, B)
    conv_mfma<C1, C2, F1, 4><<<dim3(F1 / 2 / 4, B), 256, 0, stream>>>(h1, wp2, t2, (const unsigned short*)zbuf, h2);
    // conv3: wide 1024-thr, G=8 (all 8 frames), M=128/block; LDS ~82KB (incl. pad)
    conv_mfma_wide<C2, C3, F2, 8><<<B, 1024, 0, stream>>>(h2, wp3, t3, (const unsigned short*)zbuf, h3);
    conv4_kernel<<<B, 256, 0, stream>>>(h3, w4, (float*)d_out);
}

// Round 11
// 459.919 us; speedup vs baseline: 1.4534x; 1.4534x over previous
//
#include <hip/hip_runtime.h>
#include <hip/hip_bf16.h>

#define EPS_BN 1e-5f

constexpr int B  = 2048, F0 = 64, K = 14;
constexpr int C1 = 64,  F1 = 32;
constexpr int C2 = 128, F2 = 16;
constexpr int C3 = 256, F3 = 8;

typedef __attribute__((ext_vector_type(8))) short bf16x8;
typedef __attribute__((ext_vector_type(4))) float f32x4;

__device__ __forceinline__ float bf2f(unsigned short u) {
    union { unsigned int i; float f; } x; x.i = ((unsigned int)u) << 16; return x.f;
}
__device__ __forceinline__ unsigned short f2bf(float f) {
    union { float f; unsigned int i; } x; x.f = f;
    unsigned int r = (x.i + 0x7fffu + ((x.i >> 16) & 1u)) >> 16;
    return (unsigned short)r;
}

// async global->LDS 16B copy. HW: LDS dest = wave-uniform base + lane*16.
// Callers must keep whole waves active with per-lane-consecutive dests.
__device__ __forceinline__ void gl_lds16(const void* g, void* l) {
    __builtin_amdgcn_global_load_lds(
        (const __attribute__((address_space(1))) unsigned int*)g,
        (__attribute__((address_space(3))) unsigned int*)l,
        16, 0, 0);
}

// ---- fold BN into conv1 weights; also zero the 16B pad-source block ----
__global__ void repack_w1(const float* __restrict__ w1, const float* __restrict__ g,
                          const float* __restrict__ bb, const float* __restrict__ m,
                          const float* __restrict__ v, float* __restrict__ w1f,
                          float* __restrict__ t1, float* __restrict__ zbuf) {
    int i = blockIdx.x * 256 + threadIdx.x;
    if (i < 4) zbuf[i] = 0.0f;
    if (i < C1) {
        float s = g[i] * rsqrtf(v[i] + EPS_BN);
        t1[i] = bb[i] - m[i] * s;
    }
    if (i < C1 * 2 * 9) {
        int c = i / 18;
        float s = g[c] * rsqrtf(v[c] + EPS_BN);
        w1f[i] = w1[i] * s;
    }
}

// ---- repack conv weights into MFMA B-fragment layout, bf16, BN-folded ----
// wp[((chunk*COUT + n)*32) + kk] = W[tap][ci][n]*s[n], chunk=tap*(CIN/32)+cc, ci=cc*32+kk
template<int CIN, int COUT>
__global__ void repack_mfma(const float* __restrict__ w, const float* __restrict__ g,
                            const float* __restrict__ bb, const float* __restrict__ m,
                            const float* __restrict__ v, unsigned short* __restrict__ wp,
                            float* __restrict__ t) {
    int idx = blockIdx.x * 256 + threadIdx.x;
    if (idx < COUT) {
        float s = g[idx] * rsqrtf(v[idx] + EPS_BN);
        t[idx] = bb[idx] - m[idx] * s;
    }
    if (idx < 9 * CIN * COUT) {
        constexpr int CCS = CIN / 32;
        int kk = idx & 31;
        int rest = idx >> 5;
        int n = rest & (COUT - 1);
        int chunk = rest / COUT;
        int tap = chunk / CCS;
        int cc  = chunk & (CCS - 1);
        int ci = cc * 32 + kk;
        float s = g[n] * rsqrtf(v[n] + EPS_BN);
        wp[idx] = f2bf(w[(n * CIN + ci) * 9 + tap] * s);
    }
}

// ---- conv1 (2->64, 3x3, stride (2,1), pad 1) + BN + ReLU, NHWC bf16 out ----
__global__ void conv1_kernel(const float* __restrict__ x, const float* __restrict__ sig,
                             const float* __restrict__ w1f, const float* __restrict__ t1,
                             unsigned short* __restrict__ h1) {
    __shared__ float xs[F0 * K], ssg[F0 * K], wsh[C1 * 19], bsh[C1];
    int b = blockIdx.x, t = threadIdx.x;
    for (int i = t; i < F0 * K; i += 256) {
        xs[i]  = x[(size_t)b * F0 * K + i];
        ssg[i] = sig[(size_t)b * F0 * K + i] * 10.0f;
    }
    for (int i = t; i < C1 * 18; i += 256) {
        int c = i / 18, r = i % 18;
        wsh[c * 19 + r] = w1f[i];
    }
    if (t < C1) bsh[t] = t1[t];
    __syncthreads();
    int c = t & 63, pg = t >> 6;
    for (int p = pg; p < F1 * K; p += 4) {
        int f = p / K, k = p % K;
        float acc = bsh[c];
        #pragma unroll
        for (int df = 0; df < 3; ++df) {
            int fi = 2 * f + df - 1;
            if (fi < 0 || fi >= F0) continue;
            #pragma unroll
            for (int dk = 0; dk < 3; ++dk) {
                int ki = k + dk - 1;
                if (ki < 0 || ki >= K) continue;
                acc = fmaf(xs[fi * K + ki],  wsh[c * 19 + df * 3 + dk], acc);
                acc = fmaf(ssg[fi * K + ki], wsh[c * 19 + 9 + df * 3 + dk], acc);
            }
        }
        h1[(((size_t)b * F1 + f) * K + k) * C1 + c] = f2bf(fmaxf(acc, 0.f));
    }
}

// ---- conv2 as MFMA GEMM: round-2 structure VERBATIM (proven 76 VGPR, no
// spill, 522us pipeline). G=4 per-(g,df) tiles, flat it-loop, 2-deep bv rot.
template<int CIN, int COUT, int FIN, int MINW>
__launch_bounds__(256, MINW)
__global__ void conv_mfma(const unsigned short* __restrict__ hin,
                          const unsigned short* __restrict__ wp,
                          const float* __restrict__ tb,
                          const unsigned short* __restrict__ zero16,
                          unsigned short* __restrict__ hout) {
    constexpr int G = 4;
    constexpr int CHW = CIN / 8;
    constexpr int LOGC = (CHW == 16) ? 4 : 3;
    constexpr int NT = COUT / 64;
    constexpr int CCS = CIN / 32;
    constexpr int NIT = 9 * CCS;
    __shared__ alignas(16) unsigned short lin[G * 3 * 16 * CIN];

    const int b = blockIdx.y;
    const int f2base = blockIdx.x * G;
    const int t = threadIdx.x;

    {
        constexpr int TOT = G * 3 * 16 * CHW;
        #pragma unroll
        for (int i = t; i < TOT; i += 256) {
            int c8 = i & (CHW - 1);
            int row = i >> LOGC;
            int p = row & 15;
            int tile = row >> 4;
            int df = tile % 3, g = tile / 3;
            int kin = p - 1;
            int fi = 2 * (f2base + g) + df - 1;
            bool valid = (kin >= 0) & (kin < K) & (fi >= 0);
            const unsigned short* src = valid
                ? hin + (((size_t)(b * FIN + fi)) * K + kin) * CIN + ((c8 ^ (p & 7)) << 3)
                : zero16;
            gl_lds16(src, &lin[i * 8]);
        }
    }
    __syncthreads();

    const int lane = t & 63;
    const int wave = t >> 6;
    const int m = lane & 15;
    const int quad = lane >> 4;
    const int nBase = wave * (COUT / 4);

    f32x4 acc[G][NT];
    #pragma unroll
    for (int nt = 0; nt < NT; ++nt) {
        float bias = tb[nBase + nt * 16 + m];
        #pragma unroll
        for (int g = 0; g < G; ++g)
            acc[g][nt] = f32x4{bias, bias, bias, bias};
    }

    auto loadA = [&](int it, bf16x8* av) {
        int df = it / (3 * CCS), dk = (it / CCS) % 3, cc = it % CCS;
        int p = m + dk; p = (p > 15) ? 15 : p;
        int cidx = (((cc * 4 + quad) ^ (p & 7)) << 3);
        #pragma unroll
        for (int g = 0; g < G; ++g)
            av[g] = *(const bf16x8*)&lin[((g * 3 + df) * 16 + p) * CIN + cidx];
    };
    auto loadB = [&](int it, bf16x8* bv) {
        int df = it / (3 * CCS), dk = (it / CCS) % 3, cc = it % CCS;
        int chunk = (df * 3 + dk) * CCS + cc;
        #pragma unroll
        for (int nt = 0; nt < NT; ++nt)
            bv[nt] = *(const bf16x8*)(wp + (((chunk * COUT + nBase + nt * 16 + m)) << 5) + quad * 8);
    };
    auto domfma = [&](bf16x8* av, bf16x8* bv) {
        #pragma unroll
        for (int g = 0; g < G; ++g)
            #pragma unroll
            for (int nt = 0; nt < NT; ++nt)
                acc[g][nt] = __builtin_amdgcn_mfma_f32_16x16x32_bf16(av[g], bv[nt], acc[g][nt], 0, 0, 0);
    };

    bf16x8 av[G], bA[NT], bB[NT];
    loadB(0, bA);
    #pragma unroll
    for (int it = 0; it < NIT; it += 2) {
        loadB(it + 1, bB);
        loadA(it, av);
        domfma(av, bA);
        if (it + 2 < NIT) loadB(it + 2, bA);
        loadA(it + 1, av);
        domfma(av, bB);
    }

    #pragma unroll
    for (int g = 0; g < G; ++g) {
        size_t rowbase = ((size_t)(b * (FIN / 2) + f2base + g)) * K;
        #pragma unroll
        for (int nt = 0; nt < NT; ++nt) {
            int col = nBase + nt * 16 + m;
            #pragma unroll
            for (int i = 0; i < 4; ++i) {
                int row = quad * 4 + i;
                if (row < K)
                    hout[(rowbase + row) * COUT + col] = f2bf(fmaxf(acc[g][nt][i], 0.f));
            }
        }
    }
}

// ---- conv3 + fused conv4: round-2 conv3 body, epilogue computes
// out-partials instead of storing h3. Each block holds relu(h3) for 4
// frames x 256 ch x 16 rows in acc; conv4 is a (f,c)-reduction with w4 ->
// per-thread fma into part[i][j], shfl-reduce over 16 m-lanes, LDS-reduce
// over 4 waves, one 28-float partial per block. Kills the 114MB h3 store
// and the 117MB conv4 re-read. Extra ~15 regs (76->~90 < 170 cap).
template<int CIN, int COUT, int FIN, int MINW>
__launch_bounds__(256, MINW)
__global__ void conv_mfma_fused(const unsigned short* __restrict__ hin,
                                const unsigned short* __restrict__ wp,
                                const float* __restrict__ tb,
                                const unsigned short* __restrict__ zero16,
                                const float* __restrict__ w4,
                                float* __restrict__ pb) {
    constexpr int G = 4;
    constexpr int CHW = CIN / 8;
    constexpr int LOGC = (CHW == 16) ? 4 : 3;
    constexpr int NT = COUT / 64;
    constexpr int CCS = CIN / 32;
    constexpr int NIT = 9 * CCS;
    __shared__ alignas(16) unsigned short lin[G * 3 * 16 * CIN];
    __shared__ float red[4][4][4][2];        // [wave][quad][i][j]

    const int b = blockIdx.y;
    const int f2base = blockIdx.x * G;
    const int t = threadIdx.x;

    {
        constexpr int TOT = G * 3 * 16 * CHW;
        #pragma unroll
        for (int i = t; i < TOT; i += 256) {
            int c8 = i & (CHW - 1);
            int row = i >> LOGC;
            int p = row & 15;
            int tile = row >> 4;
            int df = tile % 3, g = tile / 3;
            int kin = p - 1;
            int fi = 2 * (f2base + g) + df - 1;
            bool valid = (kin >= 0) & (kin < K) & (fi >= 0);
            const unsigned short* src = valid
                ? hin + (((size_t)(b * FIN + fi)) * K + kin) * CIN + ((c8 ^ (p & 7)) << 3)
                : zero16;
            gl_lds16(src, &lin[i * 8]);
        }
    }
    __syncthreads();

    const int lane = t & 63;
    const int wave = t >> 6;
    const int m = lane & 15;
    const int quad = lane >> 4;
    const int nBase = wave * (COUT / 4);

    f32x4 acc[G][NT];
    #pragma unroll
    for (int nt = 0; nt < NT; ++nt) {
        float bias = tb[nBase + nt * 16 + m];
        #pragma unroll
        for (int g = 0; g < G; ++g)
            acc[g][nt] = f32x4{bias, bias, bias, bias};
    }

    auto loadA = [&](int it, bf16x8* av) {
        int df = it / (3 * CCS), dk = (it / CCS) % 3, cc = it % CCS;
        int p = m + dk; p = (p > 15) ? 15 : p;
        int cidx = (((cc * 4 + quad) ^ (p & 7)) << 3);
        #pragma unroll
        for (int g = 0; g < G; ++g)
            av[g] = *(const bf16x8*)&lin[((g * 3 + df) * 16 + p) * CIN + cidx];
    };
    auto loadB = [&](int it, bf16x8* bv) {
        int df = it / (3 * CCS), dk = (it / CCS) % 3, cc = it % CCS;
        int chunk = (df * 3 + dk) * CCS + cc;
        #pragma unroll
        for (int nt = 0; nt < NT; ++nt)
            bv[nt] = *(const bf16x8*)(wp + (((chunk * COUT + nBase + nt * 16 + m)) << 5) + quad * 8);
    };
    auto domfma = [&](bf16x8* av, bf16x8* bv) {
        #pragma unroll
        for (int g = 0; g < G; ++g)
            #pragma unroll
            for (int nt = 0; nt < NT; ++nt)
                acc[g][nt] = __builtin_amdgcn_mfma_f32_16x16x32_bf16(av[g], bv[nt], acc[g][nt], 0, 0, 0);
    };

    bf16x8 av[G], bA[NT], bB[NT];
    loadB(0, bA);
    #pragma unroll
    for (int it = 0; it < NIT; it += 2) {
        loadB(it + 1, bB);
        loadA(it, av);
        domfma(av, bA);
        if (it + 2 < NIT) loadB(it + 2, bA);
        loadA(it + 1, av);
        domfma(av, bB);
    }

    // ---- fused conv4 epilogue ----
    // part[i][j] = sum over this thread's (g->f, nt->c) of relu(acc)*w4[j,c,f]
    // D row k = quad*4+i; rows 14,15 (quad==3, i>=2) are pad -> zeroed.
    float part[4][2];
    #pragma unroll
    for (int i = 0; i < 4; ++i) { part[i][0] = 0.f; part[i][1] = 0.f; }
    #pragma unroll
    for (int g = 0; g < G; ++g) {
        int f = f2base + g;
        #pragma unroll
        for (int nt = 0; nt < NT; ++nt) {
            int c = nBase + nt * 16 + m;
            float w0 = w4[(0 * COUT + c) * F3 + f];
            float w1 = w4[(1 * COUT + c) * F3 + f];
            #pragma unroll
            for (int i = 0; i < 4; ++i) {
                float v = fmaxf(acc[g][nt][i], 0.f);
                part[i][0] = fmaf(v, w0, part[i][0]);
                part[i][1] = fmaf(v, w1, part[i][1]);
            }
        }
    }
    if (quad == 3) { part[2][0] = 0.f; part[2][1] = 0.f; part[3][0] = 0.f; part[3][1] = 0.f; }
    // reduce across the 16 m-lanes (xor masks stay within the quad group)
    #pragma unroll
    for (int i = 0; i < 4; ++i)
        #pragma unroll
        for (int j = 0; j < 2; ++j) {
            float v = part[i][j];
            v += __shfl_xor(v, 1, 64);
            v += __shfl_xor(v, 2, 64);
            v += __shfl_xor(v, 4, 64);
            v += __shfl_xor(v, 8, 64);
            part[i][j] = v;
        }
    if (m == 0) {
        #pragma unroll
        for (int i = 0; i < 4; ++i) {
            red[wave][quad][i][0] = part[i][0];
            red[wave][quad][i][1] = part[i][1];
        }
    }
    __syncthreads();
    if (t < 2 * K) {
        int k = t >> 1, j = t & 1;
        float s = red[0][k >> 2][k & 3][j] + red[1][k >> 2][k & 3][j]
                + red[2][k >> 2][k & 3][j] + red[3][k >> 2][k & 3][j];
        pb[((size_t)b * 2 + blockIdx.x) * (2 * K) + t] = s;
    }
}

// ---- final: out[b,k,j] = pb[b][0][...] + pb[b][1][...] ----
__global__ void fin_kernel(const float* __restrict__ pb, float* __restrict__ out) {
    int idx = blockIdx.x * 256 + threadIdx.x;
    if (idx < B * 2 * K) {
        int b = idx / (2 * K), r = idx % (2 * K);
        out[idx] = pb[(size_t)b * (4 * K) + r] + pb[(size_t)b * (4 * K) + 2 * K + r];
    }
}

extern "C" void kernel_launch(void* const* d_in, const int* in_sizes, int n_in,
                              void* d_out, int out_size, void* d_ws, size_t ws_size,
                              hipStream_t stream) {
    const float* x   = (const float*)d_in[0];
    const float* sig = (const float*)d_in[1];
    const float* w1  = (const float*)d_in[2];
    const float* w2  = (const float*)d_in[3];
    const float* w3  = (const float*)d_in[4];
    const float* w4  = (const float*)d_in[5];
    const float* g1  = (const float*)d_in[6];
    const float* b1  = (const float*)d_in[7];
    const float* m1  = (const float*)d_in[8];
    const float* v1  = (const float*)d_in[9];
    const float* g2  = (const float*)d_in[10];
    const float* b2  = (const float*)d_in[11];
    const float* m2  = (const float*)d_in[12];
    const float* v2  = (const float*)d_in[13];
    const float* g3  = (const float*)d_in[14];
    const float* b3  = (const float*)d_in[15];
    const float* m3  = (const float*)d_in[16];
    const float* v3  = (const float*)d_in[17];

    char* ws = (char*)d_ws;
    size_t off = 0;
    auto alloc = [&](size_t bytes) {
        char* p = ws + off;
        off += (bytes + 255) & ~(size_t)255;
        return p;
    };
    unsigned short* h1  = (unsigned short*)alloc((size_t)B * F1 * K * C1 * 2);
    unsigned short* h2  = (unsigned short*)alloc((size_t)B * F2 * K * C2 * 2);
    float* w1f = (float*)alloc((size_t)C1 * 2 * 9 * 4);
    float* t1  = (float*)alloc((size_t)C1 * 4);
    unsigned short* wp2 = (unsigned short*)alloc((size_t)9 * C1 * C2 * 2);
    float* t2  = (float*)alloc((size_t)C2 * 4);
    unsigned short* wp3 = (unsigned short*)alloc((size_t)9 * C2 * C3 * 2);
    float* t3  = (float*)alloc((size_t)C3 * 4);
    float* zbuf = (float*)alloc(16);
    float* pb   = (float*)alloc((size_t)B * 2 * 2 * K * 4);   // per-block conv4 partials

    repack_w1<<<(C1 * 2 * 9 + 255) / 256, 256, 0, stream>>>(w1, g1, b1, m1, v1, w1f, t1, zbuf);
    repack_mfma<C1, C2><<<(9 * C1 * C2 + 255) / 256, 256, 0, stream>>>(w2, g2, b2, m2, v2, wp2, t2);
    repack_mfma<C2, C3><<<(9 * C2 * C3 + 255) / 256, 256, 0, stream>>>(w3, g3, b3, m3, v3, wp3, t3);

    conv1_kernel<<<B, 256, 0, stream>>>(x, sig, w1f, t1, h1);
    // conv2: round-2 structure, G=4 -> grid (4, B)
    conv_mfma<C1, C2, F1, 4><<<dim3(F1 / 2 / 4, B), 256, 0, stream>>>(h1, wp2, t2, (const unsigned short*)zbuf, h2);
    // conv3 + fused conv4: grid (2, B); writes 28-float partials per block
    conv_mfma_fused<C2, C3, F2, 3><<<dim3(F2 / 2 / 4, B), 256, 0, stream>>>(h2, wp3, t3, (const unsigned short*)zbuf, w4, pb);
    fin_kernel<<<(B * 2 * K + 255) / 256, 256, 0, stream>>>(pb, (float*)d_out);
}